// Round 14
// baseline (529.245 us; speedup 1.0000x reference)
//
#include <hip/hip_runtime.h>

#define HH 96
#define WW 96
#define CCH 256
#define NPIX (HH*WW)       // 9216
#define HP 98              // padded grid side
#define NROWS 9604         // 98*98 padded diag rows
#define CORE_LO 99         // first real padded index
#define CORE_HI 9505       // one past last real padded index
#define CAND_CAP 256

typedef unsigned short u16;
typedef _Float16 f16;
typedef _Float16 f16x8 __attribute__((ext_vector_type(8)));
typedef float f32x4 __attribute__((ext_vector_type(4)));

__device__ __forceinline__ f32x4 ld4u(const float* p) {
    f32x4 r; __builtin_memcpy(&r, p, 16); return r;
}
__device__ __forceinline__ float dec_key(unsigned ku) {
    return (ku & 0x80000000u) ? __uint_as_float(ku ^ 0x80000000u)
                              : __uint_as_float(~ku);
}
__device__ __forceinline__ unsigned enc_key(float v) {
    unsigned u = __float_as_uint(v);
    return (u & 0x80000000u) ? ~u : (u | 0x80000000u);
}
__device__ __forceinline__ int pad2m(int mp) {   // padded col -> real m
    int yq = mp / HP, xq = mp - yq * HP;
    return (yq - 1) * WW + (xq - 1);
}

// async global->LDS, 16B per lane; dst is wave-uniform slab base
__device__ __forceinline__ void stage4(const u16* const* srcs, u16* dst, int kb) {
#pragma unroll
    for (int t = 0; t < 4; ++t)
        __builtin_amdgcn_global_load_lds(
            (const __attribute__((address_space(1))) unsigned int*)(srcs[t] + kb),
            (__attribute__((address_space(3))) unsigned int*)(dst + t * 512),
            16, 0, 0);
}

// ---------- kernel 0: transpose X[c][p] -> XT[p][c] f32 AND XTh[p][c] f16 ----------
__global__ __launch_bounds__(256) void xsth_kernel(const float* __restrict__ X,
                                                   float* __restrict__ XT,
                                                   u16* __restrict__ XTh) {
    __shared__ float tile[64][65];
    const int p0 = blockIdx.x * 64, c0 = blockIdx.y * 64;
    const int rr = threadIdx.x >> 6, cl = threadIdx.x & 63;
#pragma unroll
    for (int r = 0; r < 16; ++r)
        tile[rr * 16 + r][cl] = X[(c0 + rr * 16 + r) * NPIX + p0 + cl];
    __syncthreads();
#pragma unroll
    for (int r = 0; r < 16; ++r) {
        float v = tile[cl][rr * 16 + r];
        long long o = (long long)(p0 + rr * 16 + r) * CCH + c0 + cl;
        XT[o] = v;
        f16 h = (f16)v;
        u16 hb; __builtin_memcpy(&hb, &h, 2);
        XTh[o] = hb;
    }
}

// ---------- kernel 1: per-pixel channel sum-of-squares (+ optional resets) ----------
__global__ __launch_bounds__(256) void prep_kernel(const float* __restrict__ X,
                                                   float* __restrict__ ssum,
                                                   unsigned long long* __restrict__ keys,
                                                   int* __restrict__ cnt,
                                                   unsigned* __restrict__ dropMax,
                                                   int reset) {
    int p = blockIdx.x * 256 + threadIdx.x;
    if (p >= NPIX) return;
    float s = 0.f;
#pragma unroll 8
    for (int c = 0; c < CCH; ++c) {
        float v = X[c * NPIX + p];
        s = fmaf(v, v, s);
    }
    ssum[p] = s;
    if (reset) { keys[p] = 0ULL; cnt[p] = 0; dropMax[p] = 0u; }
}

// ---------- kernel 2: per padded-col tables: rns, bias(-inf on pad) ----------
__global__ __launch_bounds__(256) void rnsbp_kernel(const float* __restrict__ ssum,
                                                    float* __restrict__ rnsp,
                                                    float* __restrict__ biasp) {
    int mp = blockIdx.x * 256 + threadIdx.x;
    if (mp >= 9632) return;
    int yq = mp / HP, xq = mp - yq * HP;
    bool real = (yq >= 1 && yq <= 96 && xq >= 1 && xq <= 96);
    if (!real) { rnsp[mp] = 0.f; biasp[mp] = -3e38f; return; }
    int y = yq - 1, x = xq - 1;
    float s = 0.f;
    for (int dy = -1; dy <= 1; ++dy) {
        int yy = y + dy;
        if ((unsigned)yy >= HH) continue;
        for (int dx = -1; dx <= 1; ++dx) {
            int xx = x + dx;
            if ((unsigned)xx >= WW) continue;
            s += ssum[yy * WW + xx];
        }
    }
    rnsp[mp] = 1.f / fmaxf(sqrtf(s), 1e-12f);
    biasp[mp] = 0.f;
}

// ---------- kernel 2b: content patch-norm band: thr[n] = 0.0036*||A_n|| ----------
__global__ __launch_bounds__(256) void cthr_kernel(const float* __restrict__ ssum,
                                                   float* __restrict__ thr) {
    int n = blockIdx.x * 256 + threadIdx.x;
    if (n >= NPIX) return;
    int y = n / WW, x = n - y * WW;
    float s = 0.f;
    for (int dy = -1; dy <= 1; ++dy) {
        int yy = y + dy;
        if ((unsigned)yy >= HH) continue;
        for (int dx = -1; dx <= 1; ++dx) {
            int xx = x + dx;
            if ((unsigned)xx >= WW) continue;
            s += ssum[yy * WW + xx];
        }
    }
    thr[n] = 0.0036f * sqrtf(s);
}

// ---------- kernel 3: zero all pad rows of the padded f32 CC buffer ----------
__global__ __launch_bounds__(256) void padzero_kernel(float* __restrict__ cc, int wstride) {
    int p = blockIdx.x;   // padded row
    int yq = p / HP, xq = p - yq * HP;
    if (yq >= 1 && yq <= 96 && xq >= 1 && xq <= 96) return;  // real row: GEMM writes it
    const f32x4 z = {0.f, 0.f, 0.f, 0.f};
    float* row = cc + (long long)p * wstride;
    for (int c = threadIdx.x * 4; c < wstride; c += 1024)
        *(f32x4*)&row[c] = z;
}

// ---------- kernel 4: coarse CC chunk GEMM, single-term f16 MFMA, f32 output ----------
__global__ __launch_bounds__(256, 5) void cc_gemm_kernel(
        const u16* __restrict__ ChT, const u16* __restrict__ ShT,
        const u16* __restrict__ zbuf,
        float* __restrict__ cc, int csp, int wstride) {
    __shared__ u16 lds[2][2][8][64][8];   // [buf][A,B][tile][lane][e] = 32 KB

    const int tid = threadIdx.x;
    const int n0 = blockIdx.x * 128;
    const int m0 = blockIdx.y * 128;
    const int wave = tid >> 6, lane = tid & 63;
    const int wr = wave >> 1, wc = wave & 1;
    const int rlo = lane & 15, kseg = (lane >> 4) * 8;
    const int isB = wave >> 1;           // waves 0,1 stage A; 2,3 stage B
    const int tb = (wave & 1) * 4;       // tile sub-block 0..3 / 4..7

    const u16* srcs[4];
    if (!isB) {
#pragma unroll
        for (int t = 0; t < 4; ++t)
            srcs[t] = ChT + (n0 + (tb + t) * 16 + rlo) * CCH + kseg;
    } else {
#pragma unroll
        for (int t = 0; t < 4; ++t) {
            int qp = csp + m0 + (tb + t) * 16 + rlo;
            int yq = qp / HP, xq = qp - yq * HP;
            bool ok = (qp < NROWS) && (yq >= 1 && yq <= 96 && xq >= 1 && xq <= 96);
            srcs[t] = ok ? (ShT + ((yq - 1) * WW + (xq - 1)) * CCH + kseg)
                         : (zbuf + kseg);
        }
    }
    u16* slab0 = &lds[0][isB][tb][0][0];
    u16* slab1 = &lds[1][isB][tb][0][0];

    f32x4 acc[4][4];
#pragma unroll
    for (int i = 0; i < 4; ++i)
#pragma unroll
        for (int j = 0; j < 4; ++j) acc[i][j] = (f32x4){0.f, 0.f, 0.f, 0.f};

    stage4(srcs, slab0, 0);
    stage4(srcs, slab1, 32);

#define READS(CUR)                                                          \
    f16x8 ah[4], bh[4];                                                     \
    _Pragma("unroll")                                                       \
    for (int i = 0; i < 4; ++i) {                                           \
        ah[i] = *(const f16x8*)&lds[CUR][0][wr * 4 + i][lane][0];           \
        bh[i] = *(const f16x8*)&lds[CUR][1][wc * 4 + i][lane][0];           \
    }

#define MFMAS                                                               \
    _Pragma("unroll")                                                       \
    for (int i = 0; i < 4; ++i)                                             \
        _Pragma("unroll")                                                   \
        for (int j = 0; j < 4; ++j)                                         \
            acc[i][j] = __builtin_amdgcn_mfma_f32_16x16x32_f16(ah[i], bh[j], acc[i][j], 0, 0, 0);

#define KSTEP(KK, WN)                                                       \
    {                                                                       \
        asm volatile("s_waitcnt vmcnt(" #WN ")" ::: "memory");              \
        __builtin_amdgcn_sched_barrier(0);                                  \
        __builtin_amdgcn_s_barrier();                                       \
        READS((KK) & 1)                                                     \
        asm volatile("s_waitcnt lgkmcnt(0)" ::: "memory");                  \
        __builtin_amdgcn_sched_barrier(0);                                  \
        __builtin_amdgcn_s_barrier();                                       \
        if ((KK) + 2 < 8)                                                   \
            stage4(srcs, (((KK) & 1)) ? slab1 : slab0, ((KK) + 2) * 32);    \
        __builtin_amdgcn_sched_barrier(0);                                  \
        MFMAS                                                               \
    }

    KSTEP(0, 4) KSTEP(1, 4) KSTEP(2, 4) KSTEP(3, 4)
    KSTEP(4, 4) KSTEP(5, 4) KSTEP(6, 4) KSTEP(7, 0)

#undef KSTEP
#undef MFMAS
#undef READS

    // C/D layout: col = lane&15, row = (lane>>4)*4 + reg. Rows -> padded p'.
    const int r0 = (lane >> 4) * 4;
    const int cl = lane & 15;
#pragma unroll
    for (int i = 0; i < 4; ++i) {
        const int prow = n0 + wr * 64 + i * 16 + r0;
#pragma unroll
        for (int r = 0; r < 4; ++r) {
            const int row = prow + r;
            const int pp = row + 2 * (row / WW) + CORE_LO;
            const long long base = (long long)pp * wstride + m0 + wc * 64 + cl;
#pragma unroll
            for (int j = 0; j < 4; ++j)
                cc[base + j * 16] = acc[i][j][r];
        }
    }
}

// ---------- kernel 5: single-pass 9-tap diag box-sum, per-lane top-2 collect ----------
__global__ __launch_bounds__(256) void boxsum_kernel(
        const float* __restrict__ cc, const float* __restrict__ rnsp,
        const float* __restrict__ biasp, const float* __restrict__ thr,
        unsigned long long* __restrict__ keys,
        int* __restrict__ cnt, float* __restrict__ candV, u16* __restrict__ candI,
        unsigned* __restrict__ dropMax,
        int core0, int coreEnd, int csp, int wstride) {
    const int wave = threadIdx.x >> 6, lane = threadIdx.x & 63;
    const int n = blockIdx.x * 4 + wave;
    const int pp = n + 2 * (n / WW) + CORE_LO;
    const long long rowbase = (long long)pp * wstride - csp;
    const int W1 = wstride + 1;
    const float thrn = thr[n];

    float wprior = -1e30f;
    {
        unsigned long long k0 = keys[n];
        if (k0) wprior = dec_key((unsigned)(k0 >> 32));
    }

    const int OFF[9] = {-99, -98, -97, -1, 0, 1, 97, 98, 99};
    const float* tp[9];
#pragma unroll
    for (int t = 0; t < 9; ++t)
        tp[t] = cc + rowbase + core0 + lane * 4 + (long long)OFF[t] * W1;

    // single sweep: per-lane top-2 values, top-1 index (padded col)
    float v1 = -3e38f, v2 = -3e38f;
    int i1 = 0;
    for (int mq = core0 + lane * 4; mq < coreEnd; mq += 256) {
        f32x4 s = {0.f, 0.f, 0.f, 0.f};
#pragma unroll
        for (int t = 0; t < 9; ++t) { s += ld4u(tp[t]); tp[t] += 256; }
        f32x4 rv = ld4u(rnsp + mq);
        f32x4 bv = ld4u(biasp + mq);
#pragma unroll
        for (int sl = 0; sl < 4; ++sl) {
            float v = fmaf(s[sl], rv[sl], bv[sl]);
            if (mq + sl >= coreEnd) v = -3e38f;
            if (v > v1) { v2 = v1; v1 = v; i1 = mq + sl; }
            else if (v > v2) v2 = v;
        }
    }

    // one wave reduce for the chunk max
    float wmax = v1;
#pragma unroll
    for (int d = 32; d; d >>= 1) wmax = fmaxf(wmax, __shfl_xor(wmax, d));
    wmax = fmaxf(wmax, wprior);
    const float lim = wmax - thrn;

    // append lane top-1 if in band
    if (v1 >= lim) {
        int idx = atomicAdd(&cnt[n], 1);
        if (idx < CAND_CAP) {
            candV[n * CAND_CAP + idx] = v1;
            candI[n * CAND_CAP + idx] = (u16)pad2m(i1);
        } else {
            atomicMax(&dropMax[n], enc_key(v1));
        }
    }
    // rare: lane's 2nd-best also in band -> rescan this lane's own share
    if (v2 >= lim) {
        const float* rp[9];
#pragma unroll
        for (int t = 0; t < 9; ++t)
            rp[t] = cc + rowbase + core0 + lane * 4 + (long long)OFF[t] * W1;
        for (int mq = core0 + lane * 4; mq < coreEnd; mq += 256) {
            f32x4 s = {0.f, 0.f, 0.f, 0.f};
#pragma unroll
            for (int t = 0; t < 9; ++t) { s += ld4u(rp[t]); rp[t] += 256; }
            f32x4 rv = ld4u(rnsp + mq);
            f32x4 bv = ld4u(biasp + mq);
#pragma unroll
            for (int sl = 0; sl < 4; ++sl) {
                float v = fmaf(s[sl], rv[sl], bv[sl]);
                if (mq + sl < coreEnd && v >= lim && (mq + sl) != i1) {
                    int idx = atomicAdd(&cnt[n], 1);
                    if (idx < CAND_CAP) {
                        candV[n * CAND_CAP + idx] = v;
                        candI[n * CAND_CAP + idx] = (u16)pad2m(mq + sl);
                    } else {
                        atomicMax(&dropMax[n], enc_key(v));
                    }
                }
            }
        }
    }
    if (lane == 0)
        atomicMax(&keys[n], ((unsigned long long)enc_key(wmax)) << 32);
}

// ---------- kernel 6: exact fp32 rescore of band candidates -> bestm ----------
__global__ __launch_bounds__(256) void rescore_kernel(
        const float* __restrict__ XcT, const float* __restrict__ XsT,
        const float* __restrict__ rnsp, const float* __restrict__ thr,
        const unsigned long long* __restrict__ keys,
        const int* __restrict__ cnt, const float* __restrict__ candV,
        const u16* __restrict__ candI, const unsigned* __restrict__ dropMax,
        int* __restrict__ bestm) {
    const int wave = threadIdx.x >> 6, lane = threadIdx.x & 63;
    const int n = blockIdx.x * 4 + wave;
    int c = cnt[n]; if (c > CAND_CAP) c = CAND_CAP;
    const float M = dec_key((unsigned)(keys[n] >> 32));
    const float lim = M - thr[n];

    unsigned dm = dropMax[n];
    bool fallback = dm && (dec_key(dm) >= lim);
    if (!fallback) {
        int npass = 0, lastk = -1;
        for (int k = 0; k < c; ++k) {
            if (candV[n * CAND_CAP + k] >= lim) { ++npass; if (lastk < 0) lastk = k; }
        }
        if (npass == 1) {
            if (lane == 0) bestm[n] = candI[n * CAND_CAP + lastk];
            return;
        }
    }

    const int yn = n / WW, xn = n - yn * WW;
    const f32x4 z = {0.f, 0.f, 0.f, 0.f};
    f32x4 an[9];
#pragma unroll
    for (int t = 0; t < 9; ++t) {
        int di = t / 3 - 1, dj = t % 3 - 1;
        bool ok = ((unsigned)(yn + di) < HH) && ((unsigned)(xn + dj) < WW);
        an[t] = ok ? ld4u(XcT + (long long)((yn + di) * WW + xn + dj) * CCH + lane * 4) : z;
    }
    float bv = -1e30f; int bm = 0x7fffffff;
    if (fallback) {
        for (int m = 0; m < NPIX; ++m) {
            int ym = m / WW, xm = m - ym * WW;
            f32x4 acc = z;
#pragma unroll
            for (int t = 0; t < 9; ++t) {
                int di = t / 3 - 1, dj = t % 3 - 1;
                if (((unsigned)(ym + di) < HH) && ((unsigned)(xm + dj) < WW))
                    acc += an[t] * ld4u(XsT + (long long)((ym + di) * WW + xm + dj) * CCH + lane * 4);
            }
            float d = acc[0] + acc[1] + acc[2] + acc[3];
#pragma unroll
            for (int dd = 32; dd; dd >>= 1) d += __shfl_xor(d, dd);
            float v = d * rnsp[(ym + 1) * HP + (xm + 1)];
            if (v > bv) { bv = v; bm = m; }   // ascending m: strict > keeps first
        }
    } else {
        for (int k = 0; k < c; ++k) {
            if (candV[n * CAND_CAP + k] < lim) continue;
            int m = candI[n * CAND_CAP + k];
            int ym = m / WW, xm = m - ym * WW;
            f32x4 acc = z;
#pragma unroll
            for (int t = 0; t < 9; ++t) {
                int di = t / 3 - 1, dj = t % 3 - 1;
                if (((unsigned)(ym + di) < HH) && ((unsigned)(xm + dj) < WW))
                    acc += an[t] * ld4u(XsT + (long long)((ym + di) * WW + xm + dj) * CCH + lane * 4);
            }
            float d = acc[0] + acc[1] + acc[2] + acc[3];
#pragma unroll
            for (int dd = 32; dd; dd >>= 1) d += __shfl_xor(d, dd);
            float v = d * rnsp[(ym + 1) * HP + (xm + 1)];
            if (v > bv || (v == bv && m < bm)) { bv = v; bm = m; }
        }
    }
    if (lane == 0) bestm[n] = bm;
}

// ---------- kernel 7: coalesced fold (one wave = one output pixel) ----------
__global__ __launch_bounds__(256) void fold2_kernel(const float* __restrict__ XsT,
                                                    const int* __restrict__ bestm,
                                                    float* __restrict__ outT) {
    const int wave = threadIdx.x >> 6, lane = threadIdx.x & 63;
    const int p = blockIdx.x * 4 + wave;
    const int y = p / WW, x = p - y * WW;
    f32x4 num = {0.f, 0.f, 0.f, 0.f};
    int den = 0;
#pragma unroll
    for (int i = 0; i < 3; ++i) {
        int ny = y + 1 - i;
        if ((unsigned)ny >= HH) continue;
#pragma unroll
        for (int j = 0; j < 3; ++j) {
            int nx = x + 1 - j;
            if ((unsigned)nx >= WW) continue;
            den++;
            int mg = bestm[ny * WW + nx];
            int my = mg / WW, mx = mg - my * WW;
            int sy = my + i - 1, sx = mx + j - 1;
            if ((unsigned)sy < HH && (unsigned)sx < WW)
                num += ld4u(XsT + (long long)(sy * WW + sx) * CCH + lane * 4);
        }
    }
    float inv = 1.f / ((float)den + 1e-8f);
    f32x4 o = {num[0] * inv, num[1] * inv, num[2] * inv, num[3] * inv};
    *(f32x4*)&outT[(long long)p * CCH + lane * 4] = o;
}

// ---------- kernel 8: transpose outT [p][c] -> out [c][p] ----------
__global__ __launch_bounds__(256) void outtr_kernel(const float* __restrict__ outT,
                                                    float* __restrict__ out) {
    __shared__ float tile[64][65];
    const int p0 = blockIdx.x * 64, c0 = blockIdx.y * 64;
    const int t = threadIdx.x;
    const int rr = t >> 6, cl = t & 63;
#pragma unroll
    for (int r = 0; r < 16; ++r)
        tile[rr * 16 + r][cl] = outT[(long long)(p0 + rr * 16 + r) * CCH + c0 + cl];
    __syncthreads();
#pragma unroll
    for (int r = 0; r < 16; ++r)
        out[(long long)(c0 + rr * 16 + r) * NPIX + p0 + cl] = tile[cl][rr * 16 + r];
}

extern "C" void kernel_launch(void* const* d_in, const int* in_sizes, int n_in,
                              void* d_out, int out_size, void* d_ws, size_t ws_size,
                              hipStream_t stream) {
    (void)in_sizes; (void)n_in; (void)out_size;
    const float* Xc = (const float*)d_in[0];
    const float* Xs = (const float*)d_in[1];
    float* out = (float*)d_out;

    char* w = (char*)d_ws;
    unsigned long long* keys = (unsigned long long*)w;  w += (size_t)NPIX * 8;
    float* XcT  = (float*)w;                            w += (size_t)NPIX * CCH * 4;
    float* XsT  = (float*)w;                            w += (size_t)NPIX * CCH * 4;
    float* outT = (float*)w;                            w += (size_t)NPIX * CCH * 4;
    u16* XcH = (u16*)w;                                 w += (size_t)NPIX * CCH * 2;
    u16* XsH = (u16*)w;                                 w += (size_t)NPIX * CCH * 2;
    float* ssum_s = (float*)w;                          w += (size_t)NPIX * 4;
    float* ssum_c = (float*)w;                          w += (size_t)NPIX * 4;
    float* rnsp  = (float*)w;                           w += (size_t)9632 * 4;
    float* biasp = (float*)w;                           w += (size_t)9632 * 4;
    float* thr   = (float*)w;                           w += (size_t)NPIX * 4;
    int*   cnt   = (int*)w;                             w += (size_t)NPIX * 4;
    int*   bestm = (int*)w;                             w += (size_t)NPIX * 4;
    unsigned* dropMax = (unsigned*)w;                   w += (size_t)NPIX * 4;
    float* candV = (float*)w;                           w += (size_t)NPIX * CAND_CAP * 4;
    u16*   candI = (u16*)w;                             w += (size_t)NPIX * CAND_CAP * 2;
    u16*   zbuf  = (u16*)w;                             w += 1024;
    float* ccbuf = (float*)w;
    const size_t fixed = (size_t)(w - (char*)d_ws);

    long long avail = (ws_size > fixed + 4096)
                        ? (long long)(ws_size - fixed - 4096) : 0;
    int wstride = (int)(((avail / ((long long)NROWS * 4)) / 128) * 128);
    if (wstride > 2560) wstride = 2560;   // f32 CC, 4 chunks, L3-resident
    if (wstride < 512) wstride = 512;
    const int McCore = wstride - 198;

    hipMemsetAsync(zbuf, 0, 1024, stream);
    dim3 gt(NPIX / 64, CCH / 64);
    xsth_kernel<<<gt, 256, 0, stream>>>(Xc, XcT, XcH);
    xsth_kernel<<<gt, 256, 0, stream>>>(Xs, XsT, XsH);
    prep_kernel<<<NPIX / 256, 256, 0, stream>>>(Xs, ssum_s, keys, cnt, dropMax, 1);
    prep_kernel<<<NPIX / 256, 256, 0, stream>>>(Xc, ssum_c, keys, cnt, dropMax, 0);
    rnsbp_kernel<<<38, 256, 0, stream>>>(ssum_s, rnsp, biasp);
    cthr_kernel<<<NPIX / 256, 256, 0, stream>>>(ssum_c, thr);
    padzero_kernel<<<NROWS, 256, 0, stream>>>(ccbuf, wstride);

    for (int core0 = CORE_LO; core0 < CORE_HI; core0 += McCore) {
        int coreEnd = (core0 + McCore < CORE_HI) ? core0 + McCore : CORE_HI;
        int csp = core0 - 99;
        int ce = coreEnd + 99; if (ce > NROWS) ce = NROWS;
        int Wc = ce - csp;
        dim3 g(NPIX / 128, (Wc + 127) / 128);
        cc_gemm_kernel<<<g, 256, 0, stream>>>(XcH, XsH, zbuf, ccbuf, csp, wstride);
        boxsum_kernel<<<NPIX / 4, 256, 0, stream>>>(ccbuf, rnsp, biasp, thr,
                                                    keys, cnt, candV, candI, dropMax,
                                                    core0, coreEnd, csp, wstride);
    }

    rescore_kernel<<<NPIX / 4, 256, 0, stream>>>(XcT, XsT, rnsp, thr, keys,
                                                 cnt, candV, candI, dropMax, bestm);
    fold2_kernel<<<NPIX / 4, 256, 0, stream>>>(XsT, bestm, outT);
    outtr_kernel<<<gt, 256, 0, stream>>>(outT, out);
}

// Round 15
// 416.445 us; speedup vs baseline: 1.2709x; 1.2709x over previous
//
#include <hip/hip_runtime.h>

#define HH 96
#define WW 96
#define CCH 256
#define NPIX (HH*WW)       // 9216
#define HP 98              // padded grid side
#define NROWS 9604         // 98*98 padded diag rows
#define CORE_LO 99         // first real padded index
#define CORE_HI 9505       // one past last real padded index
#define CAND_CAP 256

typedef unsigned short u16;
typedef _Float16 f16;
typedef _Float16 f16x8 __attribute__((ext_vector_type(8)));
typedef float f32x4 __attribute__((ext_vector_type(4)));

__device__ __forceinline__ f32x4 ld4u(const float* p) {
    f32x4 r; __builtin_memcpy(&r, p, 16); return r;
}
__device__ __forceinline__ float dec_key(unsigned ku) {
    return (ku & 0x80000000u) ? __uint_as_float(ku ^ 0x80000000u)
                              : __uint_as_float(~ku);
}
__device__ __forceinline__ unsigned enc_key(float v) {
    unsigned u = __float_as_uint(v);
    return (u & 0x80000000u) ? ~u : (u | 0x80000000u);
}
__device__ __forceinline__ int pad2m(int mp) {   // padded col -> real m
    int yq = mp / HP, xq = mp - yq * HP;
    return (yq - 1) * WW + (xq - 1);
}

// async global->LDS, 16B per lane; dst is wave-uniform slab base
__device__ __forceinline__ void stage4(const u16* const* srcs, u16* dst, int kb) {
#pragma unroll
    for (int t = 0; t < 4; ++t)
        __builtin_amdgcn_global_load_lds(
            (const __attribute__((address_space(1))) unsigned int*)(srcs[t] + kb),
            (__attribute__((address_space(3))) unsigned int*)(dst + t * 512),
            16, 0, 0);
}

// ---------- kernel 0: transpose X[c][p] -> XT[p][c] f32 AND XTh[p][c] f16 ----------
__global__ __launch_bounds__(256) void xsth_kernel(const float* __restrict__ X,
                                                   float* __restrict__ XT,
                                                   u16* __restrict__ XTh) {
    __shared__ float tile[64][65];
    const int p0 = blockIdx.x * 64, c0 = blockIdx.y * 64;
    const int rr = threadIdx.x >> 6, cl = threadIdx.x & 63;
#pragma unroll
    for (int r = 0; r < 16; ++r)
        tile[rr * 16 + r][cl] = X[(c0 + rr * 16 + r) * NPIX + p0 + cl];
    __syncthreads();
#pragma unroll
    for (int r = 0; r < 16; ++r) {
        float v = tile[cl][rr * 16 + r];
        long long o = (long long)(p0 + rr * 16 + r) * CCH + c0 + cl;
        XT[o] = v;
        f16 h = (f16)v;
        u16 hb; __builtin_memcpy(&hb, &h, 2);
        XTh[o] = hb;
    }
}

// ---------- kernel 1: per-pixel channel sum-of-squares (+ optional resets) ----------
__global__ __launch_bounds__(256) void prep_kernel(const float* __restrict__ X,
                                                   float* __restrict__ ssum,
                                                   unsigned long long* __restrict__ keys,
                                                   int* __restrict__ cnt,
                                                   unsigned* __restrict__ dropMax,
                                                   int reset) {
    int p = blockIdx.x * 256 + threadIdx.x;
    if (p >= NPIX) return;
    float s = 0.f;
#pragma unroll 8
    for (int c = 0; c < CCH; ++c) {
        float v = X[c * NPIX + p];
        s = fmaf(v, v, s);
    }
    ssum[p] = s;
    if (reset) { keys[p] = 0ULL; cnt[p] = 0; dropMax[p] = 0u; }
}

// ---------- kernel 2: per padded-col tables: rns, bias(-inf on pad) ----------
__global__ __launch_bounds__(256) void rnsbp_kernel(const float* __restrict__ ssum,
                                                    float* __restrict__ rnsp,
                                                    float* __restrict__ biasp) {
    int mp = blockIdx.x * 256 + threadIdx.x;
    if (mp >= 9632) return;
    int yq = mp / HP, xq = mp - yq * HP;
    bool real = (yq >= 1 && yq <= 96 && xq >= 1 && xq <= 96);
    if (!real) { rnsp[mp] = 0.f; biasp[mp] = -3e38f; return; }
    int y = yq - 1, x = xq - 1;
    float s = 0.f;
    for (int dy = -1; dy <= 1; ++dy) {
        int yy = y + dy;
        if ((unsigned)yy >= HH) continue;
        for (int dx = -1; dx <= 1; ++dx) {
            int xx = x + dx;
            if ((unsigned)xx >= WW) continue;
            s += ssum[yy * WW + xx];
        }
    }
    rnsp[mp] = 1.f / fmaxf(sqrtf(s), 1e-12f);
    biasp[mp] = 0.f;
}

// ---------- kernel 2b: content patch-norm band: thr[n] = 0.0036*||A_n|| ----------
__global__ __launch_bounds__(256) void cthr_kernel(const float* __restrict__ ssum,
                                                   float* __restrict__ thr) {
    int n = blockIdx.x * 256 + threadIdx.x;
    if (n >= NPIX) return;
    int y = n / WW, x = n - y * WW;
    float s = 0.f;
    for (int dy = -1; dy <= 1; ++dy) {
        int yy = y + dy;
        if ((unsigned)yy >= HH) continue;
        for (int dx = -1; dx <= 1; ++dx) {
            int xx = x + dx;
            if ((unsigned)xx >= WW) continue;
            s += ssum[yy * WW + xx];
        }
    }
    thr[n] = 0.0036f * sqrtf(s);
}

// ---------- kernel 3: zero all pad rows of the padded f32 CC buffer ----------
__global__ __launch_bounds__(256) void padzero_kernel(float* __restrict__ cc, int wstride) {
    int p = blockIdx.x;   // padded row
    int yq = p / HP, xq = p - yq * HP;
    if (yq >= 1 && yq <= 96 && xq >= 1 && xq <= 96) return;  // real row: GEMM writes it
    const f32x4 z = {0.f, 0.f, 0.f, 0.f};
    float* row = cc + (long long)p * wstride;
    for (int c = threadIdx.x * 4; c < wstride; c += 1024)
        *(f32x4*)&row[c] = z;
}

// ---------- kernel 4: coarse CC chunk GEMM, single-term f16 MFMA, f32 output ----------
__global__ __launch_bounds__(256, 4) void cc_gemm_kernel(
        const u16* __restrict__ ChT, const u16* __restrict__ ShT,
        const u16* __restrict__ zbuf,
        float* __restrict__ cc, int csp, int wstride) {
    __shared__ u16 lds[2][2][8][64][8];   // [buf][A,B][tile][lane][e] = 32 KB

    const int tid = threadIdx.x;
    const int n0 = blockIdx.x * 128;
    const int m0 = blockIdx.y * 128;
    const int wave = tid >> 6, lane = tid & 63;
    const int wr = wave >> 1, wc = wave & 1;
    const int rlo = lane & 15, kseg = (lane >> 4) * 8;
    const int isB = wave >> 1;           // waves 0,1 stage A; 2,3 stage B
    const int tb = (wave & 1) * 4;       // tile sub-block 0..3 / 4..7

    const u16* srcs[4];
    if (!isB) {
#pragma unroll
        for (int t = 0; t < 4; ++t)
            srcs[t] = ChT + (n0 + (tb + t) * 16 + rlo) * CCH + kseg;
    } else {
#pragma unroll
        for (int t = 0; t < 4; ++t) {
            int qp = csp + m0 + (tb + t) * 16 + rlo;
            int yq = qp / HP, xq = qp - yq * HP;
            bool ok = (qp < NROWS) && (yq >= 1 && yq <= 96 && xq >= 1 && xq <= 96);
            srcs[t] = ok ? (ShT + ((yq - 1) * WW + (xq - 1)) * CCH + kseg)
                         : (zbuf + kseg);
        }
    }
    u16* slab0 = &lds[0][isB][tb][0][0];
    u16* slab1 = &lds[1][isB][tb][0][0];

    f32x4 acc[4][4];
#pragma unroll
    for (int i = 0; i < 4; ++i)
#pragma unroll
        for (int j = 0; j < 4; ++j) acc[i][j] = (f32x4){0.f, 0.f, 0.f, 0.f};

    stage4(srcs, slab0, 0);
    stage4(srcs, slab1, 32);

#define READS(CUR)                                                          \
    f16x8 ah[4], bh[4];                                                     \
    _Pragma("unroll")                                                       \
    for (int i = 0; i < 4; ++i) {                                           \
        ah[i] = *(const f16x8*)&lds[CUR][0][wr * 4 + i][lane][0];           \
        bh[i] = *(const f16x8*)&lds[CUR][1][wc * 4 + i][lane][0];           \
    }

#define MFMAS                                                               \
    _Pragma("unroll")                                                       \
    for (int i = 0; i < 4; ++i)                                             \
        _Pragma("unroll")                                                   \
        for (int j = 0; j < 4; ++j)                                         \
            acc[i][j] = __builtin_amdgcn_mfma_f32_16x16x32_f16(ah[i], bh[j], acc[i][j], 0, 0, 0);

#define KSTEP(KK, WN)                                                       \
    {                                                                       \
        asm volatile("s_waitcnt vmcnt(" #WN ")" ::: "memory");              \
        __builtin_amdgcn_sched_barrier(0);                                  \
        __builtin_amdgcn_s_barrier();                                       \
        READS((KK) & 1)                                                     \
        asm volatile("s_waitcnt lgkmcnt(0)" ::: "memory");                  \
        __builtin_amdgcn_sched_barrier(0);                                  \
        __builtin_amdgcn_s_barrier();                                       \
        if ((KK) + 2 < 8)                                                   \
            stage4(srcs, (((KK) & 1)) ? slab1 : slab0, ((KK) + 2) * 32);    \
        __builtin_amdgcn_sched_barrier(0);                                  \
        MFMAS                                                               \
    }

    KSTEP(0, 4) KSTEP(1, 4) KSTEP(2, 4) KSTEP(3, 4)
    KSTEP(4, 4) KSTEP(5, 4) KSTEP(6, 4) KSTEP(7, 0)

#undef KSTEP
#undef MFMAS
#undef READS

    // C/D layout: col = lane&15, row = (lane>>4)*4 + reg. Rows -> padded p'.
    const int r0 = (lane >> 4) * 4;
    const int cl = lane & 15;
#pragma unroll
    for (int i = 0; i < 4; ++i) {
        const int prow = n0 + wr * 64 + i * 16 + r0;
#pragma unroll
        for (int r = 0; r < 4; ++r) {
            const int row = prow + r;
            const int pp = row + 2 * (row / WW) + CORE_LO;
            const long long base = (long long)pp * wstride + m0 + wc * 64 + cl;
#pragma unroll
            for (int j = 0; j < 4; ++j)
                cc[base + j * 16] = acc[i][j][r];
        }
    }
}

// ---------- kernel 5: single-pass 9-tap diag box-sum, per-lane top-2 collect ----------
__global__ __launch_bounds__(256) void boxsum_kernel(
        const float* __restrict__ cc, const float* __restrict__ rnsp,
        const float* __restrict__ biasp, const float* __restrict__ thr,
        unsigned long long* __restrict__ keys,
        int* __restrict__ cnt, float* __restrict__ candV, u16* __restrict__ candI,
        unsigned* __restrict__ dropMax,
        int core0, int coreEnd, int csp, int wstride) {
    const int wave = threadIdx.x >> 6, lane = threadIdx.x & 63;
    const int n = blockIdx.x * 4 + wave;
    const int pp = n + 2 * (n / WW) + CORE_LO;
    const long long rowbase = (long long)pp * wstride - csp;
    const int W1 = wstride + 1;
    const float thrn = thr[n];

    float wprior = -1e30f;
    {
        unsigned long long k0 = keys[n];
        if (k0) wprior = dec_key((unsigned)(k0 >> 32));
    }

    const int OFF[9] = {-99, -98, -97, -1, 0, 1, 97, 98, 99};
    const float* tp[9];
#pragma unroll
    for (int t = 0; t < 9; ++t)
        tp[t] = cc + rowbase + core0 + lane * 4 + (long long)OFF[t] * W1;

    // single sweep: per-lane top-2 values, top-1 index (padded col)
    float v1 = -3e38f, v2 = -3e38f;
    int i1 = 0;
    for (int mq = core0 + lane * 4; mq < coreEnd; mq += 256) {
        f32x4 s = {0.f, 0.f, 0.f, 0.f};
#pragma unroll
        for (int t = 0; t < 9; ++t) { s += ld4u(tp[t]); tp[t] += 256; }
        f32x4 rv = ld4u(rnsp + mq);
        f32x4 bv = ld4u(biasp + mq);
#pragma unroll
        for (int sl = 0; sl < 4; ++sl) {
            float v = fmaf(s[sl], rv[sl], bv[sl]);
            if (mq + sl >= coreEnd) v = -3e38f;
            if (v > v1) { v2 = v1; v1 = v; i1 = mq + sl; }
            else if (v > v2) v2 = v;
        }
    }

    // one wave reduce for the chunk max
    float wmax = v1;
#pragma unroll
    for (int d = 32; d; d >>= 1) wmax = fmaxf(wmax, __shfl_xor(wmax, d));
    wmax = fmaxf(wmax, wprior);
    const float lim = wmax - thrn;

    // append lane top-1 if in band
    if (v1 >= lim) {
        int idx = atomicAdd(&cnt[n], 1);
        if (idx < CAND_CAP) {
            candV[n * CAND_CAP + idx] = v1;
            candI[n * CAND_CAP + idx] = (u16)pad2m(i1);
        } else {
            atomicMax(&dropMax[n], enc_key(v1));
        }
    }
    // rare: lane's 2nd-best also in band -> rescan this lane's own share
    if (v2 >= lim) {
        const float* rp[9];
#pragma unroll
        for (int t = 0; t < 9; ++t)
            rp[t] = cc + rowbase + core0 + lane * 4 + (long long)OFF[t] * W1;
        for (int mq = core0 + lane * 4; mq < coreEnd; mq += 256) {
            f32x4 s = {0.f, 0.f, 0.f, 0.f};
#pragma unroll
            for (int t = 0; t < 9; ++t) { s += ld4u(rp[t]); rp[t] += 256; }
            f32x4 rv = ld4u(rnsp + mq);
            f32x4 bv = ld4u(biasp + mq);
#pragma unroll
            for (int sl = 0; sl < 4; ++sl) {
                float v = fmaf(s[sl], rv[sl], bv[sl]);
                if (mq + sl < coreEnd && v >= lim && (mq + sl) != i1) {
                    int idx = atomicAdd(&cnt[n], 1);
                    if (idx < CAND_CAP) {
                        candV[n * CAND_CAP + idx] = v;
                        candI[n * CAND_CAP + idx] = (u16)pad2m(mq + sl);
                    } else {
                        atomicMax(&dropMax[n], enc_key(v));
                    }
                }
            }
        }
    }
    if (lane == 0)
        atomicMax(&keys[n], ((unsigned long long)enc_key(wmax)) << 32);
}

// ---------- kernel 6: exact fp32 rescore of band candidates -> bestm ----------
__global__ __launch_bounds__(256) void rescore_kernel(
        const float* __restrict__ XcT, const float* __restrict__ XsT,
        const float* __restrict__ rnsp, const float* __restrict__ thr,
        const unsigned long long* __restrict__ keys,
        const int* __restrict__ cnt, const float* __restrict__ candV,
        const u16* __restrict__ candI, const unsigned* __restrict__ dropMax,
        int* __restrict__ bestm) {
    const int wave = threadIdx.x >> 6, lane = threadIdx.x & 63;
    const int n = blockIdx.x * 4 + wave;
    int c = cnt[n]; if (c > CAND_CAP) c = CAND_CAP;
    const float M = dec_key((unsigned)(keys[n] >> 32));
    const float lim = M - thr[n];

    unsigned dm = dropMax[n];
    bool fallback = dm && (dec_key(dm) >= lim);
    if (!fallback) {
        int npass = 0, lastk = -1;
        for (int k = 0; k < c; ++k) {
            if (candV[n * CAND_CAP + k] >= lim) { ++npass; if (lastk < 0) lastk = k; }
        }
        if (npass == 1) {
            if (lane == 0) bestm[n] = candI[n * CAND_CAP + lastk];
            return;
        }
    }

    const int yn = n / WW, xn = n - yn * WW;
    const f32x4 z = {0.f, 0.f, 0.f, 0.f};
    f32x4 an[9];
#pragma unroll
    for (int t = 0; t < 9; ++t) {
        int di = t / 3 - 1, dj = t % 3 - 1;
        bool ok = ((unsigned)(yn + di) < HH) && ((unsigned)(xn + dj) < WW);
        an[t] = ok ? ld4u(XcT + (long long)((yn + di) * WW + xn + dj) * CCH + lane * 4) : z;
    }
    float bv = -1e30f; int bm = 0x7fffffff;
    if (fallback) {
        for (int m = 0; m < NPIX; ++m) {
            int ym = m / WW, xm = m - ym * WW;
            f32x4 acc = z;
#pragma unroll
            for (int t = 0; t < 9; ++t) {
                int di = t / 3 - 1, dj = t % 3 - 1;
                if (((unsigned)(ym + di) < HH) && ((unsigned)(xm + dj) < WW))
                    acc += an[t] * ld4u(XsT + (long long)((ym + di) * WW + xm + dj) * CCH + lane * 4);
            }
            float d = acc[0] + acc[1] + acc[2] + acc[3];
#pragma unroll
            for (int dd = 32; dd; dd >>= 1) d += __shfl_xor(d, dd);
            float v = d * rnsp[(ym + 1) * HP + (xm + 1)];
            if (v > bv) { bv = v; bm = m; }   // ascending m: strict > keeps first
        }
    } else {
        for (int k = 0; k < c; ++k) {
            if (candV[n * CAND_CAP + k] < lim) continue;
            int m = candI[n * CAND_CAP + k];
            int ym = m / WW, xm = m - ym * WW;
            f32x4 acc = z;
#pragma unroll
            for (int t = 0; t < 9; ++t) {
                int di = t / 3 - 1, dj = t % 3 - 1;
                if (((unsigned)(ym + di) < HH) && ((unsigned)(xm + dj) < WW))
                    acc += an[t] * ld4u(XsT + (long long)((ym + di) * WW + xm + dj) * CCH + lane * 4);
            }
            float d = acc[0] + acc[1] + acc[2] + acc[3];
#pragma unroll
            for (int dd = 32; dd; dd >>= 1) d += __shfl_xor(d, dd);
            float v = d * rnsp[(ym + 1) * HP + (xm + 1)];
            if (v > bv || (v == bv && m < bm)) { bv = v; bm = m; }
        }
    }
    if (lane == 0) bestm[n] = bm;
}

// ---------- kernel 7: coalesced fold (one wave = one output pixel) ----------
__global__ __launch_bounds__(256) void fold2_kernel(const float* __restrict__ XsT,
                                                    const int* __restrict__ bestm,
                                                    float* __restrict__ outT) {
    const int wave = threadIdx.x >> 6, lane = threadIdx.x & 63;
    const int p = blockIdx.x * 4 + wave;
    const int y = p / WW, x = p - y * WW;
    f32x4 num = {0.f, 0.f, 0.f, 0.f};
    int den = 0;
#pragma unroll
    for (int i = 0; i < 3; ++i) {
        int ny = y + 1 - i;
        if ((unsigned)ny >= HH) continue;
#pragma unroll
        for (int j = 0; j < 3; ++j) {
            int nx = x + 1 - j;
            if ((unsigned)nx >= WW) continue;
            den++;
            int mg = bestm[ny * WW + nx];
            int my = mg / WW, mx = mg - my * WW;
            int sy = my + i - 1, sx = mx + j - 1;
            if ((unsigned)sy < HH && (unsigned)sx < WW)
                num += ld4u(XsT + (long long)(sy * WW + sx) * CCH + lane * 4);
        }
    }
    float inv = 1.f / ((float)den + 1e-8f);
    f32x4 o = {num[0] * inv, num[1] * inv, num[2] * inv, num[3] * inv};
    *(f32x4*)&outT[(long long)p * CCH + lane * 4] = o;
}

// ---------- kernel 8: transpose outT [p][c] -> out [c][p] ----------
__global__ __launch_bounds__(256) void outtr_kernel(const float* __restrict__ outT,
                                                    float* __restrict__ out) {
    __shared__ float tile[64][65];
    const int p0 = blockIdx.x * 64, c0 = blockIdx.y * 64;
    const int t = threadIdx.x;
    const int rr = t >> 6, cl = t & 63;
#pragma unroll
    for (int r = 0; r < 16; ++r)
        tile[rr * 16 + r][cl] = outT[(long long)(p0 + rr * 16 + r) * CCH + c0 + cl];
    __syncthreads();
#pragma unroll
    for (int r = 0; r < 16; ++r)
        out[(long long)(c0 + rr * 16 + r) * NPIX + p0 + cl] = tile[cl][rr * 16 + r];
}

extern "C" void kernel_launch(void* const* d_in, const int* in_sizes, int n_in,
                              void* d_out, int out_size, void* d_ws, size_t ws_size,
                              hipStream_t stream) {
    (void)in_sizes; (void)n_in; (void)out_size;
    const float* Xc = (const float*)d_in[0];
    const float* Xs = (const float*)d_in[1];
    float* out = (float*)d_out;

    char* w = (char*)d_ws;
    unsigned long long* keys = (unsigned long long*)w;  w += (size_t)NPIX * 8;
    float* XcT  = (float*)w;                            w += (size_t)NPIX * CCH * 4;
    float* XsT  = (float*)w;                            w += (size_t)NPIX * CCH * 4;
    float* outT = (float*)w;                            w += (size_t)NPIX * CCH * 4;
    u16* XcH = (u16*)w;                                 w += (size_t)NPIX * CCH * 2;
    u16* XsH = (u16*)w;                                 w += (size_t)NPIX * CCH * 2;
    float* ssum_s = (float*)w;                          w += (size_t)NPIX * 4;
    float* ssum_c = (float*)w;                          w += (size_t)NPIX * 4;
    float* rnsp  = (float*)w;                           w += (size_t)9632 * 4;
    float* biasp = (float*)w;                           w += (size_t)9632 * 4;
    float* thr   = (float*)w;                           w += (size_t)NPIX * 4;
    int*   cnt   = (int*)w;                             w += (size_t)NPIX * 4;
    int*   bestm = (int*)w;                             w += (size_t)NPIX * 4;
    unsigned* dropMax = (unsigned*)w;                   w += (size_t)NPIX * 4;
    float* candV = (float*)w;                           w += (size_t)NPIX * CAND_CAP * 4;
    u16*   candI = (u16*)w;                             w += (size_t)NPIX * CAND_CAP * 2;
    u16*   zbuf  = (u16*)w;                             w += 1024;
    float* ccbuf = (float*)w;
    const size_t fixed = (size_t)(w - (char*)d_ws);

    long long avail = (ws_size > fixed + 4096)
                        ? (long long)(ws_size - fixed - 4096) : 0;
    int wstride = (int)(((avail / ((long long)NROWS * 4)) / 128) * 128);
    if (wstride > 2560) wstride = 2560;   // f32 CC, 4 chunks, L3-resident
    if (wstride < 512) wstride = 512;
    const int McCore = wstride - 198;

    hipMemsetAsync(zbuf, 0, 1024, stream);
    dim3 gt(NPIX / 64, CCH / 64);
    xsth_kernel<<<gt, 256, 0, stream>>>(Xc, XcT, XcH);
    xsth_kernel<<<gt, 256, 0, stream>>>(Xs, XsT, XsH);
    prep_kernel<<<NPIX / 256, 256, 0, stream>>>(Xs, ssum_s, keys, cnt, dropMax, 1);
    prep_kernel<<<NPIX / 256, 256, 0, stream>>>(Xc, ssum_c, keys, cnt, dropMax, 0);
    rnsbp_kernel<<<38, 256, 0, stream>>>(ssum_s, rnsp, biasp);
    cthr_kernel<<<NPIX / 256, 256, 0, stream>>>(ssum_c, thr);
    padzero_kernel<<<NROWS, 256, 0, stream>>>(ccbuf, wstride);

    for (int core0 = CORE_LO; core0 < CORE_HI; core0 += McCore) {
        int coreEnd = (core0 + McCore < CORE_HI) ? core0 + McCore : CORE_HI;
        int csp = core0 - 99;
        int ce = coreEnd + 99; if (ce > NROWS) ce = NROWS;
        int Wc = ce - csp;
        dim3 g(NPIX / 128, (Wc + 127) / 128);
        cc_gemm_kernel<<<g, 256, 0, stream>>>(XcH, XsH, zbuf, ccbuf, csp, wstride);
        boxsum_kernel<<<NPIX / 4, 256, 0, stream>>>(ccbuf, rnsp, biasp, thr,
                                                    keys, cnt, candV, candI, dropMax,
                                                    core0, coreEnd, csp, wstride);
    }

    rescore_kernel<<<NPIX / 4, 256, 0, stream>>>(XcT, XsT, rnsp, thr, keys,
                                                 cnt, candV, candI, dropMax, bestm);
    fold2_kernel<<<NPIX / 4, 256, 0, stream>>>(XsT, bestm, outT);
    outtr_kernel<<<gt, 256, 0, stream>>>(outT, out);
}